// Round 4
// baseline (103.970 us; speedup 1.0000x reference)
//
#include <hip/hip_runtime.h>
#include <hip/hip_cooperative_groups.h>
#include <math.h>

namespace cg = cooperative_groups;

// Problem sizes (fixed): B=4, N=512, M=512, D=256
#define BB 4
#define NN 512
#define MM 512
#define DD 256

typedef short  s16x8 __attribute__((ext_vector_type(8)));
typedef __bf16 bf16x8 __attribute__((ext_vector_type(8)));
typedef float  f32x4 __attribute__((ext_vector_type(4)));
typedef unsigned short u16x4 __attribute__((ext_vector_type(4)));

static __device__ __forceinline__ f32x4 mfma16(s16x8 a, s16x8 b, f32x4 c) {
    return __builtin_amdgcn_mfma_f32_16x16x32_bf16(
        __builtin_bit_cast(bf16x8, a), __builtin_bit_cast(bf16x8, b), c, 0, 0, 0);
}

// f32 -> bf16 round-to-nearest-even
static __device__ __forceinline__ unsigned short f2b(float f) {
    union { float f; unsigned u; } v; v.f = f;
    unsigned r = v.u + 0x7FFFu + ((v.u >> 16) & 1u);
    return (unsigned short)(r >> 16);
}

// load 8 consecutive f32 (32B-aligned) and convert to a bf16 MFMA fragment
static __device__ __forceinline__ s16x8 cvt8(const float* __restrict__ p) {
    const float4 a = *(const float4*)p;
    const float4 b = *(const float4*)(p + 4);
    s16x8 r;
    r[0] = (short)f2b(a.x); r[1] = (short)f2b(a.y);
    r[2] = (short)f2b(a.z); r[3] = (short)f2b(a.w);
    r[4] = (short)f2b(b.x); r[5] = (short)f2b(b.y);
    r[6] = (short)f2b(b.z); r[7] = (short)f2b(b.w);
    return r;
}

// Single cooperative kernel, 256 blocks x 256 threads (1 block/CU, co-resident).
// Phase A: blocks [0,128): qs for 16 x-rows each; [128,256): ks + vT for 16 c-rows.
//          f32 inputs converted to bf16 in-register while building fragments.
// grid.sync()
// Phase B: 256 blocks x 8 n-rows: scores -> swizzled LDS -> PV MFMA -> residual+LN.
__global__ __launch_bounds__(256) void k_fused(
    const float* __restrict__ x, const float* __restrict__ c,
    const float* __restrict__ mask,
    const float* __restrict__ Wq, const float* __restrict__ bq,
    const float* __restrict__ Wk, const float* __restrict__ Wr,
    const float* __restrict__ Wv, const float* __restrict__ bv,
    const float* __restrict__ gamma, const float* __restrict__ beta,
    float* __restrict__ qs, float* __restrict__ ks,
    unsigned short* __restrict__ vT, float* __restrict__ out)
{
    __shared__ unsigned short w_lds[16][512];   // 16 KB score tile (bf16, swizzled)
    __shared__ float ksm[MM];                   // 2 KB
    __shared__ float h_lds[16][260];            // 16.6 KB
    __shared__ float red[4][16];

    const int tid  = threadIdx.x;
    const int lane = tid & 63, w = tid >> 6;
    const int li   = lane & 15, g = lane >> 4;

    // ================= Phase A: projections =================
    {
        const bool isk = blockIdx.x >= 128;
        const int row0 = (blockIdx.x & 127) << 4;
        const float* __restrict__ src = isk ? c : x;

        // A fragments: lane supplies A[i=li][k=g*8+t] for each of 8 k-steps
        const float* ap = src + (size_t)(row0 + li) * DD + g * 8;
        s16x8 af[8];
        #pragma unroll
        for (int kk = 0; kk < 8; ++kk) af[kk] = cvt8(ap + kk * 32);

        const int e_base = w * 64 + li;

        if (!isk) {
            f32x4 acc[4];
            const float* bp[4];
            #pragma unroll
            for (int nt = 0; nt < 4; ++nt) {
                acc[nt] = (f32x4){0.f, 0.f, 0.f, 0.f};
                bp[nt] = Wq + (size_t)(e_base + nt * 16) * DD + g * 8;
            }
            #pragma unroll
            for (int kk = 0; kk < 8; ++kk)
                #pragma unroll
                for (int nt = 0; nt < 4; ++nt)
                    acc[nt] = mfma16(af[kk], cvt8(bp[nt] + kk * 32), acc[nt]);

            float p[4] = {0.f, 0.f, 0.f, 0.f};
            #pragma unroll
            for (int nt = 0; nt < 4; ++nt) {
                const int e = e_base + nt * 16;
                const float bqe = bq[e], wre = Wr[e];
                #pragma unroll
                for (int r = 0; r < 4; ++r)
                    p[r] += wre * tanhf(acc[nt][r] + bqe);
            }
            #pragma unroll
            for (int r = 0; r < 4; ++r) {
                p[r] += __shfl_xor(p[r], 1);
                p[r] += __shfl_xor(p[r], 2);
                p[r] += __shfl_xor(p[r], 4);
                p[r] += __shfl_xor(p[r], 8);
            }
            if (li == 0) {
                #pragma unroll
                for (int r = 0; r < 4; ++r) red[w][g * 4 + r] = p[r];
            }
            __syncthreads();
            if (tid < 16)
                qs[row0 + tid] = red[0][tid] + red[1][tid] + red[2][tid] + red[3][tid];
        } else {
            f32x4 ak[4], av[4];
            const float* bpk[4];
            const float* bpv[4];
            #pragma unroll
            for (int nt = 0; nt < 4; ++nt) {
                ak[nt] = (f32x4){0.f, 0.f, 0.f, 0.f};
                av[nt] = (f32x4){0.f, 0.f, 0.f, 0.f};
                bpk[nt] = Wk + (size_t)(e_base + nt * 16) * DD + g * 8;
                bpv[nt] = Wv + (size_t)(e_base + nt * 16) * DD + g * 8;
            }
            #pragma unroll
            for (int kk = 0; kk < 8; ++kk)
                #pragma unroll
                for (int nt = 0; nt < 4; ++nt) {
                    ak[nt] = mfma16(af[kk], cvt8(bpk[nt] + kk * 32), ak[nt]);
                    av[nt] = mfma16(af[kk], cvt8(bpv[nt] + kk * 32), av[nt]);
                }

            // vT[b][e][m] bf16: lane holds m-rows m0+4g+r for col e
            const int b  = row0 >> 9;
            const int m0 = row0 & 511;
            unsigned short* vTb = vT + (size_t)b * (DD * MM);
            #pragma unroll
            for (int nt = 0; nt < 4; ++nt) {
                const int e = e_base + nt * 16;
                const float bve = bv[e];
                u16x4 o;
                #pragma unroll
                for (int r = 0; r < 4; ++r)
                    o[r] = f2b((av[nt][r] + bve) * 0.0625f);  // 1/sqrt(256)
                *(u16x4*)(vTb + (size_t)e * MM + m0 + g * 4) = o;
            }

            float p[4] = {0.f, 0.f, 0.f, 0.f};
            #pragma unroll
            for (int nt = 0; nt < 4; ++nt) {
                const int e = e_base + nt * 16;
                const float wre = Wr[e];
                #pragma unroll
                for (int r = 0; r < 4; ++r)
                    p[r] += wre * tanhf(ak[nt][r]);
            }
            #pragma unroll
            for (int r = 0; r < 4; ++r) {
                p[r] += __shfl_xor(p[r], 1);
                p[r] += __shfl_xor(p[r], 2);
                p[r] += __shfl_xor(p[r], 4);
                p[r] += __shfl_xor(p[r], 8);
            }
            if (li == 0) {
                #pragma unroll
                for (int r = 0; r < 4; ++r) red[w][g * 4 + r] = p[r];
            }
            __syncthreads();
            if (tid < 16)
                ks[row0 + tid] = red[0][tid] + red[1][tid] + red[2][tid] + red[3][tid];
        }
    }

    __threadfence();            // device-scope release of qs/ks/vT
    cg::this_grid().sync();     // cross-XCD visibility via coop barrier

    // ================= Phase B: scores + PV + residual + LN =================
    {
        const int n0g = blockIdx.x << 3;    // 8 n-rows per block
        const int b   = n0g >> 9;

        ksm[tid]       = ks[(b << 9) + tid];
        ksm[tid + 256] = ks[(b << 9) + 256 + tid];
        __syncthreads();

        // scores for rows 0..7 -> bf16 swizzled LDS (byte ^= (row&7)<<4)
        char* wbase = (char*)w_lds;
        const float* __restrict__ mrow = mask + (size_t)n0g * MM;
        #pragma unroll
        for (int it = 0; it < 16; ++it) {
            const int i = it >> 1;
            const int m = ((it & 1) << 8) + tid;
            const float qv = qs[n0g + i];
            float s = fmaxf(tanhf(qv + ksm[m]), 0.f) * mrow[(size_t)i * MM + m];
            *(unsigned short*)(wbase + (i << 10) + ((m << 1) ^ ((i & 7) << 4))) = f2b(s);
        }
        __syncthreads();

        // PV: wave w covers e-cols [w*64, w*64+64), K = 512 (16 k-steps).
        // A-tile rows 8..15 are stale LDS garbage; their D-rows are never read.
        f32x4 acc[4];
        const unsigned short* vp[4];
        #pragma unroll
        for (int nt = 0; nt < 4; ++nt) {
            acc[nt] = (f32x4){0.f, 0.f, 0.f, 0.f};
            vp[nt] = vT + (size_t)b * (DD * MM)
                        + (size_t)(w * 64 + nt * 16 + li) * MM + g * 8;
        }
        const char* arow = wbase + (li << 10);
        const int aswz = (li & 7) << 4;
        #pragma unroll
        for (int kk = 0; kk < 16; ++kk) {
            const s16x8 a = *(const s16x8*)(arow + (((kk << 6) + (g << 4)) ^ aswz));
            #pragma unroll
            for (int nt = 0; nt < 4; ++nt)
                acc[nt] = mfma16(a, *(const s16x8*)(vp[nt] + kk * 32), acc[nt]);
        }

        // scatter partial h: lane holds rows 4g+r, col e
        #pragma unroll
        for (int nt = 0; nt < 4; ++nt) {
            const int e = w * 64 + nt * 16 + li;
            #pragma unroll
            for (int r = 0; r < 4; ++r)
                h_lds[g * 4 + r][e] = acc[nt][r];
        }
        __syncthreads();

        // LN: wave w owns rows {2w, 2w+1}; lane owns 4 contiguous d
        const float4 gm = ((const float4*)gamma)[lane];
        const float4 bt = ((const float4*)beta)[lane];
        #pragma unroll
        for (int rr = 0; rr < 2; ++rr) {
            const int row = (w << 1) + rr;
            const float4 hv = *(const float4*)&h_lds[row][lane << 2];
            const float4 xv = *(const float4*)(x + ((size_t)(n0g + row)) * DD + (lane << 2));
            float4 h;
            h.x = xv.x + hv.x; h.y = xv.y + hv.y;
            h.z = xv.z + hv.z; h.w = xv.w + hv.w;
            float s  = h.x + h.y + h.z + h.w;
            float s2 = h.x * h.x + h.y * h.y + h.z * h.z + h.w * h.w;
            #pragma unroll
            for (int off = 32; off; off >>= 1) {
                s  += __shfl_xor(s, off);
                s2 += __shfl_xor(s2, off);
            }
            const float mean = s * (1.0f / DD);
            const float var  = s2 * (1.0f / DD) - mean * mean;
            const float inv  = rsqrtf(var + 1e-5f);
            float4 o;
            o.x = (h.x - mean) * inv * gm.x + bt.x;
            o.y = (h.y - mean) * inv * gm.y + bt.y;
            o.z = (h.z - mean) * inv * gm.z + bt.z;
            o.w = (h.w - mean) * inv * gm.w + bt.w;
            *(float4*)(out + ((size_t)(n0g + row)) * DD + (lane << 2)) = o;
        }
    }
}

extern "C" void kernel_launch(void* const* d_in, const int* in_sizes, int n_in,
                              void* d_out, int out_size, void* d_ws, size_t ws_size,
                              hipStream_t stream) {
    const float* x     = (const float*)d_in[0];
    const float* c     = (const float*)d_in[1];
    const float* mask  = (const float*)d_in[2];
    const float* Wq    = (const float*)d_in[3];
    const float* bq    = (const float*)d_in[4];
    const float* Wk    = (const float*)d_in[5];
    const float* Wr    = (const float*)d_in[6];
    const float* Wv    = (const float*)d_in[7];
    const float* bv    = (const float*)d_in[8];
    const float* gamma = (const float*)d_in[9];
    const float* beta  = (const float*)d_in[10];
    float* out = (float*)d_out;

    float* ws = (float*)d_ws;
    float* qs  = ws;                              // 2048 f32
    float* ksb = ws + 2048;                       // 2048 f32
    unsigned short* vT = (unsigned short*)(ws + 4096);  // 524288 bf16 [b][e][m]

    void* args[] = { (void*)&x, (void*)&c, (void*)&mask, (void*)&Wq, (void*)&bq,
                     (void*)&Wk, (void*)&Wr, (void*)&Wv, (void*)&bv,
                     (void*)&gamma, (void*)&beta,
                     (void*)&qs, (void*)&ksb, (void*)&vT, (void*)&out };
    hipLaunchCooperativeKernel((const void*)k_fused, dim3(256), dim3(256),
                               args, 0, stream);
}

// Round 5
// 38.536 us; speedup vs baseline: 2.6980x; 2.6980x over previous
//
#include <hip/hip_runtime.h>
#include <math.h>

// Problem sizes (fixed): B=4, N=512, M=512, D=256
#define BB 4
#define NN 512
#define MM 512
#define DD 256

typedef short  s16x8 __attribute__((ext_vector_type(8)));
typedef __bf16 bf16x8 __attribute__((ext_vector_type(8)));
typedef float  f32x4 __attribute__((ext_vector_type(4)));
typedef unsigned short u16x4 __attribute__((ext_vector_type(4)));

static __device__ __forceinline__ f32x4 mfma16(s16x8 a, s16x8 b, f32x4 c) {
    return __builtin_amdgcn_mfma_f32_16x16x32_bf16(
        __builtin_bit_cast(bf16x8, a), __builtin_bit_cast(bf16x8, b), c, 0, 0, 0);
}

// f32 -> bf16 round-to-nearest-even
static __device__ __forceinline__ unsigned short f2b(float f) {
    union { float f; unsigned u; } v; v.f = f;
    unsigned r = v.u + 0x7FFFu + ((v.u >> 16) & 1u);
    return (unsigned short)(r >> 16);
}

// load 8 consecutive f32 (32B-aligned) and convert to a bf16 MFMA fragment
static __device__ __forceinline__ s16x8 cvt8(const float* __restrict__ p) {
    const float4 a = *(const float4*)p;
    const float4 b = *(const float4*)(p + 4);
    s16x8 r;
    r[0] = (short)f2b(a.x); r[1] = (short)f2b(a.y);
    r[2] = (short)f2b(a.z); r[3] = (short)f2b(a.w);
    r[4] = (short)f2b(b.x); r[5] = (short)f2b(b.y);
    r[6] = (short)f2b(b.z); r[7] = (short)f2b(b.w);
    return r;
}

// ---------------- kernel 1: MFMA projections (f32 in, bf16 in-register) ----
// blocks [0,128):  qs for 16 x-rows each; [128,256): ks + vT for 16 c-rows.
// Block: 256 thr = 4 waves; wave w covers e-cols [w*64, w*64+64).
__global__ __launch_bounds__(256) void k_proj(
    const float* __restrict__ x, const float* __restrict__ c,
    const float* __restrict__ Wq, const float* __restrict__ bq,
    const float* __restrict__ Wk, const float* __restrict__ Wr,
    const float* __restrict__ Wv, const float* __restrict__ bv,
    float* __restrict__ qs, float* __restrict__ ks,
    unsigned short* __restrict__ vT)
{
    __shared__ float red[4][16];
    const int tid  = threadIdx.x;
    const int lane = tid & 63, w = tid >> 6;
    const int li   = lane & 15, g = lane >> 4;
    const bool isk = blockIdx.x >= 128;
    const int row0 = (blockIdx.x & 127) << 4;
    const float* __restrict__ src = isk ? c : x;

    // A fragments: lane supplies A[i=li][k=g*8+t] for each of 8 k-steps
    const float* ap = src + (size_t)(row0 + li) * DD + g * 8;
    s16x8 af[8];
    #pragma unroll
    for (int kk = 0; kk < 8; ++kk) af[kk] = cvt8(ap + kk * 32);

    const int e_base = w * 64 + li;

    if (!isk) {
        f32x4 acc[4];
        const float* bp[4];
        #pragma unroll
        for (int nt = 0; nt < 4; ++nt) {
            acc[nt] = (f32x4){0.f, 0.f, 0.f, 0.f};
            bp[nt] = Wq + (size_t)(e_base + nt * 16) * DD + g * 8;
        }
        #pragma unroll
        for (int kk = 0; kk < 8; ++kk)
            #pragma unroll
            for (int nt = 0; nt < 4; ++nt)
                acc[nt] = mfma16(af[kk], cvt8(bp[nt] + kk * 32), acc[nt]);

        float p[4] = {0.f, 0.f, 0.f, 0.f};
        #pragma unroll
        for (int nt = 0; nt < 4; ++nt) {
            const int e = e_base + nt * 16;
            const float bqe = bq[e], wre = Wr[e];
            #pragma unroll
            for (int r = 0; r < 4; ++r)
                p[r] += wre * tanhf(acc[nt][r] + bqe);
        }
        #pragma unroll
        for (int r = 0; r < 4; ++r) {
            p[r] += __shfl_xor(p[r], 1);
            p[r] += __shfl_xor(p[r], 2);
            p[r] += __shfl_xor(p[r], 4);
            p[r] += __shfl_xor(p[r], 8);
        }
        if (li == 0) {
            #pragma unroll
            for (int r = 0; r < 4; ++r) red[w][g * 4 + r] = p[r];
        }
        __syncthreads();
        if (tid < 16)
            qs[row0 + tid] = red[0][tid] + red[1][tid] + red[2][tid] + red[3][tid];
    } else {
        f32x4 ak[4], av[4];
        const float* bpk[4];
        const float* bpv[4];
        #pragma unroll
        for (int nt = 0; nt < 4; ++nt) {
            ak[nt] = (f32x4){0.f, 0.f, 0.f, 0.f};
            av[nt] = (f32x4){0.f, 0.f, 0.f, 0.f};
            bpk[nt] = Wk + (size_t)(e_base + nt * 16) * DD + g * 8;
            bpv[nt] = Wv + (size_t)(e_base + nt * 16) * DD + g * 8;
        }
        #pragma unroll
        for (int kk = 0; kk < 8; ++kk)
            #pragma unroll
            for (int nt = 0; nt < 4; ++nt) {
                ak[nt] = mfma16(af[kk], cvt8(bpk[nt] + kk * 32), ak[nt]);
                av[nt] = mfma16(af[kk], cvt8(bpv[nt] + kk * 32), av[nt]);
            }

        // vT[b][e][m] bf16: lane holds m-rows m0+4g+r for col e
        const int b  = row0 >> 9;
        const int m0 = row0 & 511;
        unsigned short* vTb = vT + (size_t)b * (DD * MM);
        #pragma unroll
        for (int nt = 0; nt < 4; ++nt) {
            const int e = e_base + nt * 16;
            const float bve = bv[e];
            u16x4 o;
            #pragma unroll
            for (int r = 0; r < 4; ++r)
                o[r] = f2b((av[nt][r] + bve) * 0.0625f);  // 1/sqrt(256)
            *(u16x4*)(vTb + (size_t)e * MM + m0 + g * 4) = o;
        }

        float p[4] = {0.f, 0.f, 0.f, 0.f};
        #pragma unroll
        for (int nt = 0; nt < 4; ++nt) {
            const int e = e_base + nt * 16;
            const float wre = Wr[e];
            #pragma unroll
            for (int r = 0; r < 4; ++r)
                p[r] += wre * tanhf(ak[nt][r]);
        }
        #pragma unroll
        for (int r = 0; r < 4; ++r) {
            p[r] += __shfl_xor(p[r], 1);
            p[r] += __shfl_xor(p[r], 2);
            p[r] += __shfl_xor(p[r], 4);
            p[r] += __shfl_xor(p[r], 8);
        }
        if (li == 0) {
            #pragma unroll
            for (int r = 0; r < 4; ++r) red[w][g * 4 + r] = p[r];
        }
        __syncthreads();
        if (tid < 16)
            ks[row0 + tid] = red[0][tid] + red[1][tid] + red[2][tid] + red[3][tid];
    }
}

// ---------------- kernel 2: scores + PV (MFMA) + residual + LayerNorm -----
// 256 blocks x 8 n-rows (all CUs active). LDS score tile bf16 XOR-swizzled.
// MFMA A-tile rows 8..15 are stale LDS garbage; their D-rows are never read.
__global__ __launch_bounds__(256) void k_main(
    const float* __restrict__ x, const float* __restrict__ mask,
    const float* __restrict__ qs, const float* __restrict__ ks,
    const unsigned short* __restrict__ vT,
    const float* __restrict__ gamma, const float* __restrict__ beta,
    float* __restrict__ out)
{
    __shared__ unsigned short w_lds[16][512];   // 16 KB (rows 0..7 written)
    __shared__ float ksm[MM];                   // 2 KB
    __shared__ float h_lds[16][264];            // stride 264: write conflict 2-way
                                                // (free), rows 16B-aligned
    const int tid  = threadIdx.x;
    const int lane = tid & 63, w = tid >> 6;
    const int li   = lane & 15, g = lane >> 4;
    const int n0g  = blockIdx.x << 3;           // 8 rows per block
    const int b    = n0g >> 9;

    ksm[tid]       = ks[(b << 9) + tid];
    ksm[tid + 256] = ks[(b << 9) + 256 + tid];
    __syncthreads();

    // scores rows 0..7 -> bf16 swizzled LDS (byte ^= (row&7)<<4)
    char* wbase = (char*)w_lds;
    const float* __restrict__ mrow = mask + (size_t)n0g * MM;
    #pragma unroll
    for (int it = 0; it < 16; ++it) {
        const int i = it >> 1;
        const int m = ((it & 1) << 8) + tid;
        const float qv = qs[n0g + i];
        float s = fmaxf(tanhf(qv + ksm[m]), 0.f) * mrow[(size_t)i * MM + m];
        *(unsigned short*)(wbase + (i << 10) + ((m << 1) ^ ((i & 7) << 4))) = f2b(s);
    }
    __syncthreads();

    // PV: wave w covers e-cols [w*64, w*64+64), K = 512 (16 k-steps)
    f32x4 acc[4];
    const unsigned short* vp[4];
    #pragma unroll
    for (int nt = 0; nt < 4; ++nt) {
        acc[nt] = (f32x4){0.f, 0.f, 0.f, 0.f};
        vp[nt] = vT + (size_t)b * (DD * MM)
                    + (size_t)(w * 64 + nt * 16 + li) * MM + g * 8;
    }
    const char* arow = wbase + (li << 10);
    const int aswz = (li & 7) << 4;
    #pragma unroll
    for (int kk = 0; kk < 16; ++kk) {
        const s16x8 a = *(const s16x8*)(arow + (((kk << 6) + (g << 4)) ^ aswz));
        #pragma unroll
        for (int nt = 0; nt < 4; ++nt)
            acc[nt] = mfma16(a, *(const s16x8*)(vp[nt] + kk * 32), acc[nt]);
    }

    // scatter partial h: lane holds rows 4g+r, col e
    #pragma unroll
    for (int nt = 0; nt < 4; ++nt) {
        const int e = w * 64 + nt * 16 + li;
        #pragma unroll
        for (int r = 0; r < 4; ++r)
            h_lds[g * 4 + r][e] = acc[nt][r];
    }
    __syncthreads();

    // LN: wave w owns rows {2w, 2w+1}; lane owns 4 contiguous d
    const float4 gm = ((const float4*)gamma)[lane];
    const float4 bt = ((const float4*)beta)[lane];
    #pragma unroll
    for (int rr = 0; rr < 2; ++rr) {
        const int row = (w << 1) + rr;
        const float4 hv = *(const float4*)&h_lds[row][lane << 2];
        const float4 xv = *(const float4*)(x + ((size_t)(n0g + row)) * DD + (lane << 2));
        float4 h;
        h.x = xv.x + hv.x; h.y = xv.y + hv.y;
        h.z = xv.z + hv.z; h.w = xv.w + hv.w;
        float s  = h.x + h.y + h.z + h.w;
        float s2 = h.x * h.x + h.y * h.y + h.z * h.z + h.w * h.w;
        #pragma unroll
        for (int off = 32; off; off >>= 1) {
            s  += __shfl_xor(s, off);
            s2 += __shfl_xor(s2, off);
        }
        const float mean = s * (1.0f / DD);
        const float var  = s2 * (1.0f / DD) - mean * mean;
        const float inv  = rsqrtf(var + 1e-5f);
        float4 o;
        o.x = (h.x - mean) * inv * gm.x + bt.x;
        o.y = (h.y - mean) * inv * gm.y + bt.y;
        o.z = (h.z - mean) * inv * gm.z + bt.z;
        o.w = (h.w - mean) * inv * gm.w + bt.w;
        *(float4*)(out + ((size_t)(n0g + row)) * DD + (lane << 2)) = o;
    }
}

extern "C" void kernel_launch(void* const* d_in, const int* in_sizes, int n_in,
                              void* d_out, int out_size, void* d_ws, size_t ws_size,
                              hipStream_t stream) {
    const float* x     = (const float*)d_in[0];
    const float* c     = (const float*)d_in[1];
    const float* mask  = (const float*)d_in[2];
    const float* Wq    = (const float*)d_in[3];
    const float* bq    = (const float*)d_in[4];
    const float* Wk    = (const float*)d_in[5];
    const float* Wr    = (const float*)d_in[6];
    const float* Wv    = (const float*)d_in[7];
    const float* bv    = (const float*)d_in[8];
    const float* gamma = (const float*)d_in[9];
    const float* beta  = (const float*)d_in[10];
    float* out = (float*)d_out;

    float* ws = (float*)d_ws;
    float* qs  = ws;                                    // 2048 f32
    float* ksb = ws + 2048;                             // 2048 f32
    unsigned short* vT = (unsigned short*)(ws + 4096);  // 524288 bf16 [b][e][m]

    k_proj<<<256, 256, 0, stream>>>(x, c, Wq, bq, Wk, Wr, Wv, bv, qs, ksb, vT);
    k_main<<<256, 256, 0, stream>>>(x, mask, qs, ksb, vT, gamma, beta, out);
}